// Round 10
// baseline (828.450 us; speedup 1.0000x reference)
//
#include <hip/hip_runtime.h>
#include <math.h>

#define NQ 100000
#define NA 100000
#define EDGES 1000000
#define LSUP 250000
#define IN_DIM 128
#define C_DIM 64
#define SCAN_BS 1024
#define NBLK ((NQ + SCAN_BS - 1) / SCAN_BS)   // 98

// gelu (exact, approximate=False): 0.5*x*(1+erf(x/sqrt(2)))
static __device__ __forceinline__ float geluf(float x) {
    return 0.5f * x * (1.0f + erff(x * 0.70710678118654752440f));
}

// ---------------------------------------------------------------------------
// Fold per-relation a_rel/m_rel [H,D,D] into the K/V projection weights:
//   Weff[c][h*32+e] = (sum_d W[c][h*32+d] * rel[h][d][e]) * colscale(h)
//   beff[h*32+e]    = (sum_d b[h*32+d]    * rel[h][d][e]) * colscale(h)
// colscale(h) = p_rel[h]/sqrt(D) for the K-path (prel != nullptr), else 1.
// ---------------------------------------------------------------------------
__global__ void fuse_weights_kernel(const float* __restrict__ W, const float* __restrict__ b,
                                    const float* __restrict__ rel, const float* __restrict__ prel,
                                    float* __restrict__ Weff, float* __restrict__ beff)
{
    int i = blockIdx.x * blockDim.x + threadIdx.x;
    if (i < 64 * 64) {
        int c = i >> 6, j = i & 63;
        int h = j >> 5, e2 = j & 31;
        float cs = prel ? prel[h] * 0.17677669529663688110f : 1.0f;  // 1/sqrt(32)
        const float* wrow = W + c * 64 + h * 32;
        const float* r = rel + h * 1024 + e2;
        float s = 0.f;
        #pragma unroll
        for (int d = 0; d < 32; ++d) s += wrow[d] * r[d * 32];
        Weff[i] = s * cs;
    } else if (i < 64 * 64 + 64) {
        int j = i - 64 * 64;
        int h = j >> 5, e2 = j & 31;
        float cs = prel ? prel[h] * 0.17677669529663688110f : 1.0f;
        const float* r = rel + h * 1024 + e2;
        float s = 0.f;
        #pragma unroll
        for (int d = 0; d < 32; ++d) s += b[h * 32 + d] * r[d * 32];
        beff[j] = s * cs;
    }
}

// ---------------------------------------------------------------------------
// Input projection + ReLU:  Y[n,64] = relu(X[n,128] @ W[128,64] + b)
// ---------------------------------------------------------------------------
__global__ __launch_bounds__(256) void inproj_kernel(
    const float* __restrict__ X, const float* __restrict__ W, const float* __restrict__ b,
    float* __restrict__ Y, int n)
{
    __shared__ float sX[64][IN_DIM + 1];
    __shared__ float sW[IN_DIM][64];
    int tid = threadIdx.x;
    int row0 = blockIdx.x * 64;

    for (int i = tid; i < IN_DIM * 16; i += 256) {
        int k = i >> 4, c4 = i & 15;
        float4 w = ((const float4*)W)[i];
        sW[k][c4 * 4 + 0] = w.x; sW[k][c4 * 4 + 1] = w.y;
        sW[k][c4 * 4 + 2] = w.z; sW[k][c4 * 4 + 3] = w.w;
    }
    for (int i = tid; i < 64 * (IN_DIM / 4); i += 256) {
        int r = i >> 5, kc = i & 31;
        int row = row0 + r;
        float4 v = make_float4(0.f, 0.f, 0.f, 0.f);
        if (row < n) v = ((const float4*)X)[(size_t)row * (IN_DIM / 4) + kc];
        sX[r][kc * 4 + 0] = v.x; sX[r][kc * 4 + 1] = v.y;
        sX[r][kc * 4 + 2] = v.z; sX[r][kc * 4 + 3] = v.w;
    }
    __syncthreads();

    int tr = tid >> 4, tc = tid & 15;
    float acc[4][4] = {};
    #pragma unroll 4
    for (int k = 0; k < IN_DIM; ++k) {
        float4 w4 = *(const float4*)&sW[k][tc * 4];
        float a0 = sX[tr * 4 + 0][k], a1 = sX[tr * 4 + 1][k];
        float a2 = sX[tr * 4 + 2][k], a3 = sX[tr * 4 + 3][k];
        acc[0][0] += a0 * w4.x; acc[0][1] += a0 * w4.y; acc[0][2] += a0 * w4.z; acc[0][3] += a0 * w4.w;
        acc[1][0] += a1 * w4.x; acc[1][1] += a1 * w4.y; acc[1][2] += a1 * w4.z; acc[1][3] += a1 * w4.w;
        acc[2][0] += a2 * w4.x; acc[2][1] += a2 * w4.y; acc[2][2] += a2 * w4.z; acc[2][3] += a2 * w4.w;
        acc[3][0] += a3 * w4.x; acc[3][1] += a3 * w4.y; acc[3][2] += a3 * w4.z; acc[3][3] += a3 * w4.w;
    }
    float4 b4 = *(const float4*)&b[tc * 4];
    #pragma unroll
    for (int r = 0; r < 4; ++r) {
        int row = row0 + tr * 4 + r;
        if (row < n) {
            float4 o;
            o.x = fmaxf(acc[r][0] + b4.x, 0.f);
            o.y = fmaxf(acc[r][1] + b4.y, 0.f);
            o.z = fmaxf(acc[r][2] + b4.z, 0.f);
            o.w = fmaxf(acc[r][3] + b4.w, 0.f);
            ((float4*)Y)[(size_t)row * 16 + tc] = o;
        }
    }
}

// ---------------------------------------------------------------------------
// Three 64x64 projections in one pass: KK, QQ, VV (rel transforms pre-folded)
// ---------------------------------------------------------------------------
__global__ __launch_bounds__(256) void proj3_kernel(
    const float* __restrict__ Xh,
    const float* __restrict__ Wk, const float* __restrict__ bk,
    const float* __restrict__ Wq, const float* __restrict__ bq,
    const float* __restrict__ Wv, const float* __restrict__ bv,
    float* __restrict__ KK, float* __restrict__ QQ, float* __restrict__ VV, int n)
{
    __shared__ float sX[64][65];
    __shared__ float sW[3][64][64];
    int tid = threadIdx.x;
    int row0 = blockIdx.x * 64;

    for (int i = tid; i < 64 * 16; i += 256) {
        int k = i >> 4, c4 = i & 15;
        float4 w0 = ((const float4*)Wk)[i];
        float4 w1 = ((const float4*)Wq)[i];
        float4 w2 = ((const float4*)Wv)[i];
        sW[0][k][c4 * 4 + 0] = w0.x; sW[0][k][c4 * 4 + 1] = w0.y; sW[0][k][c4 * 4 + 2] = w0.z; sW[0][k][c4 * 4 + 3] = w0.w;
        sW[1][k][c4 * 4 + 0] = w1.x; sW[1][k][c4 * 4 + 1] = w1.y; sW[1][k][c4 * 4 + 2] = w1.z; sW[1][k][c4 * 4 + 3] = w1.w;
        sW[2][k][c4 * 4 + 0] = w2.x; sW[2][k][c4 * 4 + 1] = w2.y; sW[2][k][c4 * 4 + 2] = w2.z; sW[2][k][c4 * 4 + 3] = w2.w;
    }
    for (int i = tid; i < 64 * 16; i += 256) {
        int r = i >> 4, kc = i & 15;
        int row = row0 + r;
        float4 v = make_float4(0.f, 0.f, 0.f, 0.f);
        if (row < n) v = ((const float4*)Xh)[(size_t)row * 16 + kc];
        sX[r][kc * 4 + 0] = v.x; sX[r][kc * 4 + 1] = v.y; sX[r][kc * 4 + 2] = v.z; sX[r][kc * 4 + 3] = v.w;
    }
    __syncthreads();

    int tr = tid >> 4, tc = tid & 15;
    float acc[3][4][4] = {};
    #pragma unroll 4
    for (int k = 0; k < 64; ++k) {
        float a0 = sX[tr * 4 + 0][k], a1 = sX[tr * 4 + 1][k];
        float a2 = sX[tr * 4 + 2][k], a3 = sX[tr * 4 + 3][k];
        #pragma unroll
        for (int mmat = 0; mmat < 3; ++mmat) {
            float4 w4 = *(const float4*)&sW[mmat][k][tc * 4];
            acc[mmat][0][0] += a0 * w4.x; acc[mmat][0][1] += a0 * w4.y; acc[mmat][0][2] += a0 * w4.z; acc[mmat][0][3] += a0 * w4.w;
            acc[mmat][1][0] += a1 * w4.x; acc[mmat][1][1] += a1 * w4.y; acc[mmat][1][2] += a1 * w4.z; acc[mmat][1][3] += a1 * w4.w;
            acc[mmat][2][0] += a2 * w4.x; acc[mmat][2][1] += a2 * w4.y; acc[mmat][2][2] += a2 * w4.z; acc[mmat][2][3] += a2 * w4.w;
            acc[mmat][3][0] += a3 * w4.x; acc[mmat][3][1] += a3 * w4.y; acc[mmat][3][2] += a3 * w4.z; acc[mmat][3][3] += a3 * w4.w;
        }
    }
    float4 bk4 = *(const float4*)&bk[tc * 4];
    float4 bq4 = *(const float4*)&bq[tc * 4];
    float4 bv4 = *(const float4*)&bv[tc * 4];
    #pragma unroll
    for (int r = 0; r < 4; ++r) {
        int row = row0 + tr * 4 + r;
        if (row < n) {
            float4 o;
            o.x = acc[0][r][0] + bk4.x; o.y = acc[0][r][1] + bk4.y; o.z = acc[0][r][2] + bk4.z; o.w = acc[0][r][3] + bk4.w;
            ((float4*)KK)[(size_t)row * 16 + tc] = o;
            o.x = acc[1][r][0] + bq4.x; o.y = acc[1][r][1] + bq4.y; o.z = acc[1][r][2] + bq4.z; o.w = acc[1][r][3] + bq4.w;
            ((float4*)QQ)[(size_t)row * 16 + tc] = o;
            o.x = acc[2][r][0] + bv4.x; o.y = acc[2][r][1] + bv4.y; o.z = acc[2][r][2] + bv4.z; o.w = acc[2][r][3] + bv4.w;
            ((float4*)VV)[(size_t)row * 16 + tc] = o;
        }
    }
}

// ---------------------------------------------------------------------------
// CSR build: histogram over dst, 3-pass parallel exclusive scan, scatter of
// packed int2 {src, bits(w)} records (ONE 8B store per edge -> one dirtied
// cache line per edge instead of two; Round-8 counters showed 102 MB
// WRITE_SIZE from 8 MB of payload with split 4B stores).
// hist/scatter handle both edge types in one dispatch via gridDim.y.
// ---------------------------------------------------------------------------
__global__ void zero_kernel(int* __restrict__ a, int na, int* __restrict__ b, int nb)
{
    int stride = gridDim.x * blockDim.x;
    for (int i = blockIdx.x * blockDim.x + threadIdx.x; i < na + nb; i += stride) {
        if (i < na) a[i] = 0; else b[i - na] = 0;
    }
}

__global__ void hist2_kernel(const int* __restrict__ ei0, int* __restrict__ cnt0,
                             const int* __restrict__ ei1, int* __restrict__ cnt1, int E)
{
    const int* ei = blockIdx.y ? ei1 : ei0;
    int* cnt      = blockIdx.y ? cnt1 : cnt0;
    int stride = gridDim.x * blockDim.x;
    for (int e = blockIdx.x * blockDim.x + threadIdx.x; e < E; e += stride)
        atomicAdd(&cnt[ei[E + e]], 1);
}

// pass 1: per-block exclusive scan of 1024 elements; emit block sums
__global__ __launch_bounds__(SCAN_BS) void scan1_kernel(
    const int* __restrict__ cnt, int* __restrict__ off, int* __restrict__ partials, int n)
{
    __shared__ int s[SCAN_BS];
    int seg = blockIdx.y;
    int tid = threadIdx.x;
    int i = blockIdx.x * SCAN_BS + tid;
    int v = (i < n) ? cnt[(size_t)seg * n + i] : 0;
    s[tid] = v;
    __syncthreads();
    #pragma unroll
    for (int ofs = 1; ofs < SCAN_BS; ofs <<= 1) {
        int t = (tid >= ofs) ? s[tid - ofs] : 0;
        __syncthreads();
        s[tid] += t;
        __syncthreads();
    }
    if (i < n) off[(size_t)seg * n + i] = s[tid] - v;   // exclusive
    if (tid == SCAN_BS - 1) partials[seg * NBLK + blockIdx.x] = s[tid];
}

// pass 2: exclusive scan of the NBLK block sums (one block per segment)
__global__ __launch_bounds__(128) void scan2_kernel(int* __restrict__ partials)
{
    __shared__ int s[128];
    int seg = blockIdx.x;
    int tid = threadIdx.x;
    int v = (tid < NBLK) ? partials[seg * NBLK + tid] : 0;
    s[tid] = v;
    __syncthreads();
    #pragma unroll
    for (int ofs = 1; ofs < 128; ofs <<= 1) {
        int t = (tid >= ofs) ? s[tid - ofs] : 0;
        __syncthreads();
        s[tid] += t;
        __syncthreads();
    }
    if (tid < NBLK) partials[seg * NBLK + tid] = s[tid] - v;   // exclusive
}

// pass 3: add scanned block offsets back
__global__ __launch_bounds__(SCAN_BS) void scan3_kernel(
    int* __restrict__ off, const int* __restrict__ partials, int n)
{
    int seg = blockIdx.y;
    int i = blockIdx.x * SCAN_BS + threadIdx.x;
    if (i < n) off[(size_t)seg * n + i] += partials[seg * NBLK + blockIdx.x];
}

__global__ void scatter2_kernel(
    const int* __restrict__ ei0, const float* __restrict__ w0, int* __restrict__ off0, int2* __restrict__ csr0,
    const int* __restrict__ ei1, const float* __restrict__ w1, int* __restrict__ off1, int2* __restrict__ csr1,
    int E)
{
    const int* ei = blockIdx.y ? ei1 : ei0;
    const float* w = blockIdx.y ? w1 : w0;
    int* off = blockIdx.y ? off1 : off0;
    int2* csr = blockIdx.y ? csr1 : csr0;
    int stride = gridDim.x * blockDim.x;
    for (int e = blockIdx.x * blockDim.x + threadIdx.x; e < E; e += stride) {
        int dst = ei[E + e];
        int pos = atomicAdd(&off[dst], 1);   // off becomes end-offset after this pass
        csr[pos] = make_int2(ei[e], __float_as_int(w[e]));
    }
}

// ---------------------------------------------------------------------------
// Fused aggregation: one pass per dst node (16-lane group), online softmax,
// 1-deep software-pipelined gathers. p_rel/sqrt(D) pre-folded into kk.
// CSR record is packed int2 {src, bits(w)} -> one 8B load per edge.
// NOTE: qd and agg may ALIAS (group g reads qd[g] once at entry, writes agg[g]
// once at exit) — so no __restrict__ on those two parameters.
// ---------------------------------------------------------------------------
__global__ __launch_bounds__(256) void agg_kernel(
    const float* __restrict__ kk, const float* __restrict__ vv, const float* qd,
    const int2* __restrict__ csr,
    const int* __restrict__ off_end, const int* __restrict__ cnt,
    float* agg, int n_dst)
{
    int lane = threadIdx.x & 15;
    int g = (blockIdx.x * blockDim.x + threadIdx.x) >> 4;
    if (g >= n_dst) return;
    float4 q4 = ((const float4*)qd)[(size_t)g * 16 + lane];
    int e_end = off_end[g];
    int b = e_end - cnt[g];
    float m = -3.0e38f;
    float ssum = 0.f;
    float ax = 0.f, ay = 0.f, az = 0.f, aw = 0.f;

    if (b < e_end) {
        int2 rec = csr[b];
        float4 k4 = ((const float4*)kk)[(size_t)rec.x * 16 + lane];
        float4 v4 = ((const float4*)vv)[(size_t)rec.x * 16 + lane];
        for (int e = b; e < e_end; ++e) {
            float4 kc = k4, vc = v4;
            float wc = __int_as_float(rec.y);
            if (e + 1 < e_end) {               // issue next-edge gathers early
                rec = csr[e + 1];
                k4 = ((const float4*)kk)[(size_t)rec.x * 16 + lane];
                v4 = ((const float4*)vv)[(size_t)rec.x * 16 + lane];
            }
            float p = q4.x * kc.x + q4.y * kc.y + q4.z * kc.z + q4.w * kc.w;
            p += __shfl_xor(p, 1);
            p += __shfl_xor(p, 2);
            p += __shfl_xor(p, 4);   // 8-lane head subgroup now holds alpha
            float ee;
            if (p > m) {             // subgroup-uniform branch
                float scale = expf(m - p);   // first hit: exp(-huge) -> 0
                ssum *= scale; ax *= scale; ay *= scale; az *= scale; aw *= scale;
                m = p;
                ee = 1.0f;
            } else {
                ee = expf(p - m);
            }
            ssum += ee;
            float wg = ee * wc;
            ax += vc.x * wg; ay += vc.y * wg; az += vc.z * wg; aw += vc.w * wg;
        }
    }
    float inv = 1.0f / (ssum + 1e-16f);
    float4 o = make_float4(ax * inv, ay * inv, az * inv, aw * inv);
    ((float4*)agg)[(size_t)g * 16 + lane] = o;   // empty group -> 0 (matches ref)
}

// ---------------------------------------------------------------------------
// Update: z = beta*(gelu(agg)@Wa + ba) + (1-beta)*x,  beta = sigmoid(skip)
// ---------------------------------------------------------------------------
__global__ __launch_bounds__(256) void update_kernel(
    const float* __restrict__ agg, const float* __restrict__ x,
    const float* __restrict__ Wa, const float* __restrict__ ba,
    const float* __restrict__ skip, float* __restrict__ z, int n)
{
    __shared__ float sG[64][65];
    __shared__ float sW[64][64];
    int tid = threadIdx.x;
    int row0 = blockIdx.x * 64;

    for (int i = tid; i < 64 * 16; i += 256) {
        int k = i >> 4, c4 = i & 15;
        float4 w = ((const float4*)Wa)[i];
        sW[k][c4 * 4 + 0] = w.x; sW[k][c4 * 4 + 1] = w.y;
        sW[k][c4 * 4 + 2] = w.z; sW[k][c4 * 4 + 3] = w.w;
    }
    for (int i = tid; i < 64 * 16; i += 256) {
        int r = i >> 4, kc = i & 15;
        int row = row0 + r;
        float4 v = make_float4(0.f, 0.f, 0.f, 0.f);
        if (row < n) v = ((const float4*)agg)[(size_t)row * 16 + kc];
        sG[r][kc * 4 + 0] = geluf(v.x); sG[r][kc * 4 + 1] = geluf(v.y);
        sG[r][kc * 4 + 2] = geluf(v.z); sG[r][kc * 4 + 3] = geluf(v.w);
    }
    __syncthreads();

    float beta = 1.f / (1.f + expf(-skip[0]));
    int tr = tid >> 4, tc = tid & 15;
    float acc[4][4] = {};
    #pragma unroll 4
    for (int k = 0; k < 64; ++k) {
        float4 w4 = *(const float4*)&sW[k][tc * 4];
        float a0 = sG[tr * 4 + 0][k], a1 = sG[tr * 4 + 1][k];
        float a2 = sG[tr * 4 + 2][k], a3 = sG[tr * 4 + 3][k];
        acc[0][0] += a0 * w4.x; acc[0][1] += a0 * w4.y; acc[0][2] += a0 * w4.z; acc[0][3] += a0 * w4.w;
        acc[1][0] += a1 * w4.x; acc[1][1] += a1 * w4.y; acc[1][2] += a1 * w4.z; acc[1][3] += a1 * w4.w;
        acc[2][0] += a2 * w4.x; acc[2][1] += a2 * w4.y; acc[2][2] += a2 * w4.z; acc[2][3] += a2 * w4.w;
        acc[3][0] += a3 * w4.x; acc[3][1] += a3 * w4.y; acc[3][2] += a3 * w4.z; acc[3][3] += a3 * w4.w;
    }
    float4 b4 = *(const float4*)&ba[tc * 4];
    float omb = 1.f - beta;
    #pragma unroll
    for (int r = 0; r < 4; ++r) {
        int row = row0 + tr * 4 + r;
        if (row < n) {
            float4 xv = ((const float4*)x)[(size_t)row * 16 + tc];
            float4 o;
            o.x = beta * (acc[r][0] + b4.x) + omb * xv.x;
            o.y = beta * (acc[r][1] + b4.y) + omb * xv.y;
            o.z = beta * (acc[r][2] + b4.z) + omb * xv.z;
            o.w = beta * (acc[r][3] + b4.w) + omb * xv.w;
            ((float4*)z)[(size_t)row * 16 + tc] = o;
        }
    }
}

// ---------------------------------------------------------------------------
// Decoder: out[i] = sigmoid( zq[s_i] · za[d_i] ), 16 lanes per pair.
// ---------------------------------------------------------------------------
__global__ __launch_bounds__(256) void decoder_kernel(
    const float* __restrict__ zq, const float* __restrict__ za,
    const int* __restrict__ eli, float* __restrict__ out, int L)
{
    int lane = threadIdx.x & 15;
    int pair = (blockIdx.x * blockDim.x + threadIdx.x) >> 4;
    if (pair >= L) return;
    int s = eli[pair], d = eli[L + pair];
    float4 a = ((const float4*)zq)[(size_t)s * 16 + lane];
    float4 b = ((const float4*)za)[(size_t)d * 16 + lane];
    float p = a.x * b.x + a.y * b.y + a.z * b.z + a.w * b.w;
    p += __shfl_xor(p, 1);
    p += __shfl_xor(p, 2);
    p += __shfl_xor(p, 4);
    p += __shfl_xor(p, 8);
    if (lane == 0) out[pair] = 1.f / (1.f + expf(-p));
}

// ---------------------------------------------------------------------------

extern "C" void kernel_launch(void* const* d_in, const int* in_sizes, int n_in,
                              void* d_out, int out_size, void* d_ws, size_t ws_size,
                              hipStream_t stream)
{
    (void)in_sizes; (void)n_in; (void)out_size;

    const float* x_question = (const float*)d_in[0];
    const float* x_answer   = (const float*)d_in[1];
    const int*   ei_qa      = (const int*)d_in[2];
    const int*   ei_aq      = (const int*)d_in[3];
    const float* w_qa       = (const float*)d_in[4];
    const float* w_aq       = (const float*)d_in[5];
    const int*   eli        = (const int*)d_in[6];
    const float* W_in_q = (const float*)d_in[7],  *b_in_q = (const float*)d_in[8];
    const float* Wk_q = (const float*)d_in[9],  *bk_q = (const float*)d_in[10];
    const float* Wq_q = (const float*)d_in[11], *bq_q = (const float*)d_in[12];
    const float* Wv_q = (const float*)d_in[13], *bv_q = (const float*)d_in[14];
    const float* Wa_q = (const float*)d_in[15], *ba_q = (const float*)d_in[16];
    const float* skip_q = (const float*)d_in[17];
    const float* W_in_a = (const float*)d_in[18], *b_in_a = (const float*)d_in[19];
    const float* Wk_a = (const float*)d_in[20], *bk_a = (const float*)d_in[21];
    const float* Wq_a = (const float*)d_in[22], *bq_a = (const float*)d_in[23];
    const float* Wv_a = (const float*)d_in[24], *bv_a = (const float*)d_in[25];
    const float* Wa_a = (const float*)d_in[26], *ba_a = (const float*)d_in[27];
    const float* skip_a = (const float*)d_in[28];
    const float* a_rel_qa = (const float*)d_in[29];
    const float* m_rel_qa = (const float*)d_in[30];
    const float* p_rel_qa = (const float*)d_in[31];
    const float* a_rel_aq = (const float*)d_in[32];
    const float* m_rel_aq = (const float*)d_in[33];
    const float* p_rel_aq = (const float*)d_in[34];

    float* out = (float*)d_out;

    // ---- workspace layout (f32 elements), ~222.5 MB; guard keeps failures visible ----
    const size_t NEEDED =
        (8ull * NQ * 64 + 4ull * EDGES + 4ull * NQ + 2ull * NBLK + 4ull * (64 * 64 + 64)) * 4ull;
    if (ws_size < NEEDED) return;

    float* ws = (float*)d_ws;
    size_t o = 0;
    auto alloc = [&](size_t nelem) { float* p = ws + o; o += nelem; return p; };
    float* xq   = alloc((size_t)NQ * 64);
    float* xa   = alloc((size_t)NA * 64);
    float* kkq  = alloc((size_t)NQ * 64);   // reused as zq after agg
    float* qqn  = alloc((size_t)NQ * 64);   // reused as aggq (safe alias in agg_kernel)
    float* vvq  = alloc((size_t)NQ * 64);
    float* kka  = alloc((size_t)NA * 64);   // reused as za after agg
    float* qan  = alloc((size_t)NA * 64);   // reused as agga
    float* vva  = alloc((size_t)NA * 64);
    int2*  csr_qa = (int2*)alloc(2ull * EDGES);   // packed {src, bits(w)}
    int2*  csr_aq = (int2*)alloc(2ull * EDGES);
    int* cnt_qa = (int*)alloc(NA);          // cnt_aq must immediately follow (scan uses base+seg*n)
    int* cnt_aq = (int*)alloc(NQ);
    int* off_qa = (int*)alloc(NA);          // off_aq must immediately follow
    int* off_aq = (int*)alloc(NQ);
    int* partials = (int*)alloc(2 * NBLK);
    float* wk_eff_q = alloc(64 * 64); float* bk_eff_q = alloc(64);
    float* wv_eff_q = alloc(64 * 64); float* bv_eff_q = alloc(64);
    float* wk_eff_a = alloc(64 * 64); float* bk_eff_a = alloc(64);
    float* wv_eff_a = alloc(64 * 64); float* bv_eff_a = alloc(64);

    float* aggq = qqn;   // aliases (see agg_kernel note)
    float* agga = qan;
    float* zq = kkq;     // kk dead after agg
    float* za = kka;

    const int rowsblk = (NQ + 63) / 64;          // 1563 (NQ == NA)
    const int aggblk  = (NQ * 16 + 255) / 256;   // 6250

    // 1) zero histograms
    zero_kernel<<<784, 256, 0, stream>>>(cnt_qa, NA, cnt_aq, NQ);

    // 2) fold a_rel/m_rel (and p_rel/sqrt(D) for K) into projection weights
    fuse_weights_kernel<<<17, 256, 0, stream>>>(Wk_q, bk_q, a_rel_qa, p_rel_qa, wk_eff_q, bk_eff_q);
    fuse_weights_kernel<<<17, 256, 0, stream>>>(Wv_q, bv_q, m_rel_qa, nullptr,  wv_eff_q, bv_eff_q);
    fuse_weights_kernel<<<17, 256, 0, stream>>>(Wk_a, bk_a, a_rel_aq, p_rel_aq, wk_eff_a, bk_eff_a);
    fuse_weights_kernel<<<17, 256, 0, stream>>>(Wv_a, bv_a, m_rel_aq, nullptr,  wv_eff_a, bv_eff_a);

    // 3) input projections + relu
    inproj_kernel<<<rowsblk, 256, 0, stream>>>(x_question, W_in_q, b_in_q, xq, NQ);
    inproj_kernel<<<rowsblk, 256, 0, stream>>>(x_answer,   W_in_a, b_in_a, xa, NA);

    // 4) K/Q/V projections
    proj3_kernel<<<rowsblk, 256, 0, stream>>>(xq, wk_eff_q, bk_eff_q, Wq_q, bq_q,
                                              wv_eff_q, bv_eff_q, kkq, qqn, vvq, NQ);
    proj3_kernel<<<rowsblk, 256, 0, stream>>>(xa, wk_eff_a, bk_eff_a, Wq_a, bq_a,
                                              wv_eff_a, bv_eff_a, kka, qan, vva, NA);

    // 5) CSR build for both edge types (hist/scan/scatter batched via grid.y)
    hist2_kernel<<<dim3(1024, 2), 256, 0, stream>>>(ei_qa, cnt_qa, ei_aq, cnt_aq, EDGES);
    scan1_kernel<<<dim3(NBLK, 2), SCAN_BS, 0, stream>>>(cnt_qa, off_qa, partials, NQ);
    scan2_kernel<<<2, 128, 0, stream>>>(partials);
    scan3_kernel<<<dim3(NBLK, 2), SCAN_BS, 0, stream>>>(off_qa, partials, NQ);
    scatter2_kernel<<<dim3(1024, 2), 256, 0, stream>>>(ei_qa, w_qa, off_qa, csr_qa,
                                                       ei_aq, w_aq, off_aq, csr_aq, EDGES);

    // 6) fused edge aggregation (gather-based, online softmax, atomic-free)
    agg_kernel<<<aggblk, 256, 0, stream>>>(kkq, vvq, qan, csr_qa, off_qa, cnt_qa, agga, NA);
    agg_kernel<<<aggblk, 256, 0, stream>>>(kka, vva, qqn, csr_aq, off_aq, cnt_aq, aggq, NQ);

    // 7) node update (gelu + linear + gated skip)
    update_kernel<<<rowsblk, 256, 0, stream>>>(aggq, xq, Wa_q, ba_q, skip_q, zq, NQ);
    update_kernel<<<rowsblk, 256, 0, stream>>>(agga, xa, Wa_a, ba_a, skip_a, za, NA);

    // 8) decoder
    decoder_kernel<<<(LSUP * 16 + 255) / 256, 256, 0, stream>>>(zq, za, eli, out, LSUP);
}

// Round 14
// 733.028 us; speedup vs baseline: 1.1302x; 1.1302x over previous
//
#include <hip/hip_runtime.h>
#include <math.h>

#define NQ 100000
#define NA 100000
#define EDGES 1000000
#define LSUP 250000
#define IN_DIM 128
#define C_DIM 64
#define SCAN_BS 1024
#define NBLK ((NQ + SCAN_BS - 1) / SCAN_BS)   // 98

// gelu (exact, approximate=False): 0.5*x*(1+erf(x/sqrt(2)))
static __device__ __forceinline__ float geluf(float x) {
    return 0.5f * x * (1.0f + erff(x * 0.70710678118654752440f));
}

// ---------------------------------------------------------------------------
// Fold per-relation a_rel/m_rel [H,D,D] into the K/V projection weights:
//   Weff[c][h*32+e] = (sum_d W[c][h*32+d] * rel[h][d][e]) * colscale(h)
//   beff[h*32+e]    = (sum_d b[h*32+d]    * rel[h][d][e]) * colscale(h)
// colscale(h) = p_rel[h]/sqrt(D) for the K-path (prel != nullptr), else 1.
// ---------------------------------------------------------------------------
__global__ void fuse_weights_kernel(const float* __restrict__ W, const float* __restrict__ b,
                                    const float* __restrict__ rel, const float* __restrict__ prel,
                                    float* __restrict__ Weff, float* __restrict__ beff)
{
    int i = blockIdx.x * blockDim.x + threadIdx.x;
    if (i < 64 * 64) {
        int c = i >> 6, j = i & 63;
        int h = j >> 5, e2 = j & 31;
        float cs = prel ? prel[h] * 0.17677669529663688110f : 1.0f;  // 1/sqrt(32)
        const float* wrow = W + c * 64 + h * 32;
        const float* r = rel + h * 1024 + e2;
        float s = 0.f;
        #pragma unroll
        for (int d = 0; d < 32; ++d) s += wrow[d] * r[d * 32];
        Weff[i] = s * cs;
    } else if (i < 64 * 64 + 64) {
        int j = i - 64 * 64;
        int h = j >> 5, e2 = j & 31;
        float cs = prel ? prel[h] * 0.17677669529663688110f : 1.0f;
        const float* r = rel + h * 1024 + e2;
        float s = 0.f;
        #pragma unroll
        for (int d = 0; d < 32; ++d) s += b[h * 32 + d] * r[d * 32];
        beff[j] = s * cs;
    }
}

// ---------------------------------------------------------------------------
// Input projection + ReLU:  Y[n,64] = relu(X[n,128] @ W[128,64] + b)
// ---------------------------------------------------------------------------
__global__ __launch_bounds__(256) void inproj_kernel(
    const float* __restrict__ X, const float* __restrict__ W, const float* __restrict__ b,
    float* __restrict__ Y, int n)
{
    __shared__ float sX[64][IN_DIM + 1];
    __shared__ float sW[IN_DIM][64];
    int tid = threadIdx.x;
    int row0 = blockIdx.x * 64;

    for (int i = tid; i < IN_DIM * 16; i += 256) {
        int k = i >> 4, c4 = i & 15;
        float4 w = ((const float4*)W)[i];
        sW[k][c4 * 4 + 0] = w.x; sW[k][c4 * 4 + 1] = w.y;
        sW[k][c4 * 4 + 2] = w.z; sW[k][c4 * 4 + 3] = w.w;
    }
    for (int i = tid; i < 64 * (IN_DIM / 4); i += 256) {
        int r = i >> 5, kc = i & 31;
        int row = row0 + r;
        float4 v = make_float4(0.f, 0.f, 0.f, 0.f);
        if (row < n) v = ((const float4*)X)[(size_t)row * (IN_DIM / 4) + kc];
        sX[r][kc * 4 + 0] = v.x; sX[r][kc * 4 + 1] = v.y;
        sX[r][kc * 4 + 2] = v.z; sX[r][kc * 4 + 3] = v.w;
    }
    __syncthreads();

    int tr = tid >> 4, tc = tid & 15;
    float acc[4][4] = {};
    #pragma unroll 4
    for (int k = 0; k < IN_DIM; ++k) {
        float4 w4 = *(const float4*)&sW[k][tc * 4];
        float a0 = sX[tr * 4 + 0][k], a1 = sX[tr * 4 + 1][k];
        float a2 = sX[tr * 4 + 2][k], a3 = sX[tr * 4 + 3][k];
        acc[0][0] += a0 * w4.x; acc[0][1] += a0 * w4.y; acc[0][2] += a0 * w4.z; acc[0][3] += a0 * w4.w;
        acc[1][0] += a1 * w4.x; acc[1][1] += a1 * w4.y; acc[1][2] += a1 * w4.z; acc[1][3] += a1 * w4.w;
        acc[2][0] += a2 * w4.x; acc[2][1] += a2 * w4.y; acc[2][2] += a2 * w4.z; acc[2][3] += a2 * w4.w;
        acc[3][0] += a3 * w4.x; acc[3][1] += a3 * w4.y; acc[3][2] += a3 * w4.z; acc[3][3] += a3 * w4.w;
    }
    float4 b4 = *(const float4*)&b[tc * 4];
    #pragma unroll
    for (int r = 0; r < 4; ++r) {
        int row = row0 + tr * 4 + r;
        if (row < n) {
            float4 o;
            o.x = fmaxf(acc[r][0] + b4.x, 0.f);
            o.y = fmaxf(acc[r][1] + b4.y, 0.f);
            o.z = fmaxf(acc[r][2] + b4.z, 0.f);
            o.w = fmaxf(acc[r][3] + b4.w, 0.f);
            ((float4*)Y)[(size_t)row * 16 + tc] = o;
        }
    }
}

// ---------------------------------------------------------------------------
// Three 64x64 projections in one pass: KK, QQ, VV (rel transforms pre-folded)
// ---------------------------------------------------------------------------
__global__ __launch_bounds__(256) void proj3_kernel(
    const float* __restrict__ Xh,
    const float* __restrict__ Wk, const float* __restrict__ bk,
    const float* __restrict__ Wq, const float* __restrict__ bq,
    const float* __restrict__ Wv, const float* __restrict__ bv,
    float* __restrict__ KK, float* __restrict__ QQ, float* __restrict__ VV, int n)
{
    __shared__ float sX[64][65];
    __shared__ float sW[3][64][64];
    int tid = threadIdx.x;
    int row0 = blockIdx.x * 64;

    for (int i = tid; i < 64 * 16; i += 256) {
        int k = i >> 4, c4 = i & 15;
        float4 w0 = ((const float4*)Wk)[i];
        float4 w1 = ((const float4*)Wq)[i];
        float4 w2 = ((const float4*)Wv)[i];
        sW[0][k][c4 * 4 + 0] = w0.x; sW[0][k][c4 * 4 + 1] = w0.y; sW[0][k][c4 * 4 + 2] = w0.z; sW[0][k][c4 * 4 + 3] = w0.w;
        sW[1][k][c4 * 4 + 0] = w1.x; sW[1][k][c4 * 4 + 1] = w1.y; sW[1][k][c4 * 4 + 2] = w1.z; sW[1][k][c4 * 4 + 3] = w1.w;
        sW[2][k][c4 * 4 + 0] = w2.x; sW[2][k][c4 * 4 + 1] = w2.y; sW[2][k][c4 * 4 + 2] = w2.z; sW[2][k][c4 * 4 + 3] = w2.w;
    }
    for (int i = tid; i < 64 * 16; i += 256) {
        int r = i >> 4, kc = i & 15;
        int row = row0 + r;
        float4 v = make_float4(0.f, 0.f, 0.f, 0.f);
        if (row < n) v = ((const float4*)Xh)[(size_t)row * 16 + kc];
        sX[r][kc * 4 + 0] = v.x; sX[r][kc * 4 + 1] = v.y; sX[r][kc * 4 + 2] = v.z; sX[r][kc * 4 + 3] = v.w;
    }
    __syncthreads();

    int tr = tid >> 4, tc = tid & 15;
    float acc[3][4][4] = {};
    #pragma unroll 4
    for (int k = 0; k < 64; ++k) {
        float a0 = sX[tr * 4 + 0][k], a1 = sX[tr * 4 + 1][k];
        float a2 = sX[tr * 4 + 2][k], a3 = sX[tr * 4 + 3][k];
        #pragma unroll
        for (int mmat = 0; mmat < 3; ++mmat) {
            float4 w4 = *(const float4*)&sW[mmat][k][tc * 4];
            acc[mmat][0][0] += a0 * w4.x; acc[mmat][0][1] += a0 * w4.y; acc[mmat][0][2] += a0 * w4.z; acc[mmat][0][3] += a0 * w4.w;
            acc[mmat][1][0] += a1 * w4.x; acc[mmat][1][1] += a1 * w4.y; acc[mmat][1][2] += a1 * w4.z; acc[mmat][1][3] += a1 * w4.w;
            acc[mmat][2][0] += a2 * w4.x; acc[mmat][2][1] += a2 * w4.y; acc[mmat][2][2] += a2 * w4.z; acc[mmat][2][3] += a2 * w4.w;
            acc[mmat][3][0] += a3 * w4.x; acc[mmat][3][1] += a3 * w4.y; acc[mmat][3][2] += a3 * w4.z; acc[mmat][3][3] += a3 * w4.w;
        }
    }
    float4 bk4 = *(const float4*)&bk[tc * 4];
    float4 bq4 = *(const float4*)&bq[tc * 4];
    float4 bv4 = *(const float4*)&bv[tc * 4];
    #pragma unroll
    for (int r = 0; r < 4; ++r) {
        int row = row0 + tr * 4 + r;
        if (row < n) {
            float4 o;
            o.x = acc[0][r][0] + bk4.x; o.y = acc[0][r][1] + bk4.y; o.z = acc[0][r][2] + bk4.z; o.w = acc[0][r][3] + bk4.w;
            ((float4*)KK)[(size_t)row * 16 + tc] = o;
            o.x = acc[1][r][0] + bq4.x; o.y = acc[1][r][1] + bq4.y; o.z = acc[1][r][2] + bq4.z; o.w = acc[1][r][3] + bq4.w;
            ((float4*)QQ)[(size_t)row * 16 + tc] = o;
            o.x = acc[2][r][0] + bv4.x; o.y = acc[2][r][1] + bv4.y; o.z = acc[2][r][2] + bv4.z; o.w = acc[2][r][3] + bv4.w;
            ((float4*)VV)[(size_t)row * 16 + tc] = o;
        }
    }
}

// ---------------------------------------------------------------------------
// CSR build, atomic-minimized (Round-10 counters: time scales with atomic
// count at ~12 G/s; store traffic is NOT the limit):
//   hist2:  rank[e] = atomicAdd(cnt[dst],1)   (the ONLY atomics, 1 per edge)
//   scan:   off = exclusive_scan(cnt)          (off stays read-only)
//   scatter2: pos = off[dst] + rank[e]         (NO atomics, streaming)
// hist/scatter handle both edge types in one dispatch via gridDim.y.
// ---------------------------------------------------------------------------
__global__ void zero_kernel(int* __restrict__ a, int na, int* __restrict__ b, int nb)
{
    int stride = gridDim.x * blockDim.x;
    for (int i = blockIdx.x * blockDim.x + threadIdx.x; i < na + nb; i += stride) {
        if (i < na) a[i] = 0; else b[i - na] = 0;
    }
}

__global__ void hist2_kernel(const int* __restrict__ ei0, int* __restrict__ cnt0, int* __restrict__ rank0,
                             const int* __restrict__ ei1, int* __restrict__ cnt1, int* __restrict__ rank1,
                             int E)
{
    const int* ei = blockIdx.y ? ei1 : ei0;
    int* cnt      = blockIdx.y ? cnt1 : cnt0;
    int* rank     = blockIdx.y ? rank1 : rank0;
    int stride = gridDim.x * blockDim.x;
    for (int e = blockIdx.x * blockDim.x + threadIdx.x; e < E; e += stride)
        rank[e] = atomicAdd(&cnt[ei[E + e]], 1);
}

// pass 1: per-block exclusive scan of 1024 elements; emit block sums
__global__ __launch_bounds__(SCAN_BS) void scan1_kernel(
    const int* __restrict__ cnt, int* __restrict__ off, int* __restrict__ partials, int n)
{
    __shared__ int s[SCAN_BS];
    int seg = blockIdx.y;
    int tid = threadIdx.x;
    int i = blockIdx.x * SCAN_BS + tid;
    int v = (i < n) ? cnt[(size_t)seg * n + i] : 0;
    s[tid] = v;
    __syncthreads();
    #pragma unroll
    for (int ofs = 1; ofs < SCAN_BS; ofs <<= 1) {
        int t = (tid >= ofs) ? s[tid - ofs] : 0;
        __syncthreads();
        s[tid] += t;
        __syncthreads();
    }
    if (i < n) off[(size_t)seg * n + i] = s[tid] - v;   // exclusive
    if (tid == SCAN_BS - 1) partials[seg * NBLK + blockIdx.x] = s[tid];
}

// pass 2: exclusive scan of the NBLK block sums (one block per segment)
__global__ __launch_bounds__(128) void scan2_kernel(int* __restrict__ partials)
{
    __shared__ int s[128];
    int seg = blockIdx.x;
    int tid = threadIdx.x;
    int v = (tid < NBLK) ? partials[seg * NBLK + tid] : 0;
    s[tid] = v;
    __syncthreads();
    #pragma unroll
    for (int ofs = 1; ofs < 128; ofs <<= 1) {
        int t = (tid >= ofs) ? s[tid - ofs] : 0;
        __syncthreads();
        s[tid] += t;
        __syncthreads();
    }
    if (tid < NBLK) partials[seg * NBLK + tid] = s[tid] - v;   // exclusive
}

// pass 3: add scanned block offsets back
__global__ __launch_bounds__(SCAN_BS) void scan3_kernel(
    int* __restrict__ off, const int* __restrict__ partials, int n)
{
    int seg = blockIdx.y;
    int i = blockIdx.x * SCAN_BS + threadIdx.x;
    if (i < n) off[(size_t)seg * n + i] += partials[seg * NBLK + blockIdx.x];
}

__global__ void scatter2_kernel(
    const int* __restrict__ ei0, const float* __restrict__ w0, const int* __restrict__ rank0,
    const int* __restrict__ off0, int2* __restrict__ csr0,
    const int* __restrict__ ei1, const float* __restrict__ w1, const int* __restrict__ rank1,
    const int* __restrict__ off1, int2* __restrict__ csr1,
    int E)
{
    const int* ei = blockIdx.y ? ei1 : ei0;
    const float* w = blockIdx.y ? w1 : w0;
    const int* rank = blockIdx.y ? rank1 : rank0;
    const int* off = blockIdx.y ? off1 : off0;
    int2* csr = blockIdx.y ? csr1 : csr0;
    int stride = gridDim.x * blockDim.x;
    for (int e = blockIdx.x * blockDim.x + threadIdx.x; e < E; e += stride) {
        int dst = ei[E + e];
        int pos = off[dst] + rank[e];        // no atomic: rank assigned in hist2
        csr[pos] = make_int2(ei[e], __float_as_int(w[e]));
    }
}

// ---------------------------------------------------------------------------
// Fused aggregation: one pass per dst node (16-lane group), online softmax,
// 1-deep software-pipelined gathers. p_rel/sqrt(D) pre-folded into kk.
// CSR record is packed int2 {src, bits(w)}; segment g = [off[g], off[g]+cnt[g]).
// NOTE: qd and agg may ALIAS (group g reads qd[g] once at entry, writes agg[g]
// once at exit) — so no __restrict__ on those two parameters.
// ---------------------------------------------------------------------------
__global__ __launch_bounds__(256) void agg_kernel(
    const float* __restrict__ kk, const float* __restrict__ vv, const float* qd,
    const int2* __restrict__ csr,
    const int* __restrict__ off, const int* __restrict__ cnt,
    float* agg, int n_dst)
{
    int lane = threadIdx.x & 15;
    int g = (blockIdx.x * blockDim.x + threadIdx.x) >> 4;
    if (g >= n_dst) return;
    float4 q4 = ((const float4*)qd)[(size_t)g * 16 + lane];
    int b = off[g];
    int e_end = b + cnt[g];
    float m = -3.0e38f;
    float ssum = 0.f;
    float ax = 0.f, ay = 0.f, az = 0.f, aw = 0.f;

    if (b < e_end) {
        int2 rec = csr[b];
        float4 k4 = ((const float4*)kk)[(size_t)rec.x * 16 + lane];
        float4 v4 = ((const float4*)vv)[(size_t)rec.x * 16 + lane];
        for (int e = b; e < e_end; ++e) {
            float4 kc = k4, vc = v4;
            float wc = __int_as_float(rec.y);
            if (e + 1 < e_end) {               // issue next-edge gathers early
                rec = csr[e + 1];
                k4 = ((const float4*)kk)[(size_t)rec.x * 16 + lane];
                v4 = ((const float4*)vv)[(size_t)rec.x * 16 + lane];
            }
            float p = q4.x * kc.x + q4.y * kc.y + q4.z * kc.z + q4.w * kc.w;
            p += __shfl_xor(p, 1);
            p += __shfl_xor(p, 2);
            p += __shfl_xor(p, 4);   // 8-lane head subgroup now holds alpha
            float ee;
            if (p > m) {             // subgroup-uniform branch
                float scale = expf(m - p);   // first hit: exp(-huge) -> 0
                ssum *= scale; ax *= scale; ay *= scale; az *= scale; aw *= scale;
                m = p;
                ee = 1.0f;
            } else {
                ee = expf(p - m);
            }
            ssum += ee;
            float wg = ee * wc;
            ax += vc.x * wg; ay += vc.y * wg; az += vc.z * wg; aw += vc.w * wg;
        }
    }
    float inv = 1.0f / (ssum + 1e-16f);
    float4 o = make_float4(ax * inv, ay * inv, az * inv, aw * inv);
    ((float4*)agg)[(size_t)g * 16 + lane] = o;   // empty group -> 0 (matches ref)
}

// ---------------------------------------------------------------------------
// Update: z = beta*(gelu(agg)@Wa + ba) + (1-beta)*x,  beta = sigmoid(skip)
// ---------------------------------------------------------------------------
__global__ __launch_bounds__(256) void update_kernel(
    const float* __restrict__ agg, const float* __restrict__ x,
    const float* __restrict__ Wa, const float* __restrict__ ba,
    const float* __restrict__ skip, float* __restrict__ z, int n)
{
    __shared__ float sG[64][65];
    __shared__ float sW[64][64];
    int tid = threadIdx.x;
    int row0 = blockIdx.x * 64;

    for (int i = tid; i < 64 * 16; i += 256) {
        int k = i >> 4, c4 = i & 15;
        float4 w = ((const float4*)Wa)[i];
        sW[k][c4 * 4 + 0] = w.x; sW[k][c4 * 4 + 1] = w.y;
        sW[k][c4 * 4 + 2] = w.z; sW[k][c4 * 4 + 3] = w.w;
    }
    for (int i = tid; i < 64 * 16; i += 256) {
        int r = i >> 4, kc = i & 15;
        int row = row0 + r;
        float4 v = make_float4(0.f, 0.f, 0.f, 0.f);
        if (row < n) v = ((const float4*)agg)[(size_t)row * 16 + kc];
        sG[r][kc * 4 + 0] = geluf(v.x); sG[r][kc * 4 + 1] = geluf(v.y);
        sG[r][kc * 4 + 2] = geluf(v.z); sG[r][kc * 4 + 3] = geluf(v.w);
    }
    __syncthreads();

    float beta = 1.f / (1.f + expf(-skip[0]));
    int tr = tid >> 4, tc = tid & 15;
    float acc[4][4] = {};
    #pragma unroll 4
    for (int k = 0; k < 64; ++k) {
        float4 w4 = *(const float4*)&sW[k][tc * 4];
        float a0 = sG[tr * 4 + 0][k], a1 = sG[tr * 4 + 1][k];
        float a2 = sG[tr * 4 + 2][k], a3 = sG[tr * 4 + 3][k];
        acc[0][0] += a0 * w4.x; acc[0][1] += a0 * w4.y; acc[0][2] += a0 * w4.z; acc[0][3] += a0 * w4.w;
        acc[1][0] += a1 * w4.x; acc[1][1] += a1 * w4.y; acc[1][2] += a1 * w4.z; acc[1][3] += a1 * w4.w;
        acc[2][0] += a2 * w4.x; acc[2][1] += a2 * w4.y; acc[2][2] += a2 * w4.z; acc[2][3] += a2 * w4.w;
        acc[3][0] += a3 * w4.x; acc[3][1] += a3 * w4.y; acc[3][2] += a3 * w4.z; acc[3][3] += a3 * w4.w;
    }
    float4 b4 = *(const float4*)&ba[tc * 4];
    float omb = 1.f - beta;
    #pragma unroll
    for (int r = 0; r < 4; ++r) {
        int row = row0 + tr * 4 + r;
        if (row < n) {
            float4 xv = ((const float4*)x)[(size_t)row * 16 + tc];
            float4 o;
            o.x = beta * (acc[r][0] + b4.x) + omb * xv.x;
            o.y = beta * (acc[r][1] + b4.y) + omb * xv.y;
            o.z = beta * (acc[r][2] + b4.z) + omb * xv.z;
            o.w = beta * (acc[r][3] + b4.w) + omb * xv.w;
            ((float4*)z)[(size_t)row * 16 + tc] = o;
        }
    }
}

// ---------------------------------------------------------------------------
// Decoder: out[i] = sigmoid( zq[s_i] · za[d_i] ), 16 lanes per pair.
// ---------------------------------------------------------------------------
__global__ __launch_bounds__(256) void decoder_kernel(
    const float* __restrict__ zq, const float* __restrict__ za,
    const int* __restrict__ eli, float* __restrict__ out, int L)
{
    int lane = threadIdx.x & 15;
    int pair = (blockIdx.x * blockDim.x + threadIdx.x) >> 4;
    if (pair >= L) return;
    int s = eli[pair], d = eli[L + pair];
    float4 a = ((const float4*)zq)[(size_t)s * 16 + lane];
    float4 b = ((const float4*)za)[(size_t)d * 16 + lane];
    float p = a.x * b.x + a.y * b.y + a.z * b.z + a.w * b.w;
    p += __shfl_xor(p, 1);
    p += __shfl_xor(p, 2);
    p += __shfl_xor(p, 4);
    p += __shfl_xor(p, 8);
    if (lane == 0) out[pair] = 1.f / (1.f + expf(-p));
}

// ---------------------------------------------------------------------------

extern "C" void kernel_launch(void* const* d_in, const int* in_sizes, int n_in,
                              void* d_out, int out_size, void* d_ws, size_t ws_size,
                              hipStream_t stream)
{
    (void)in_sizes; (void)n_in; (void)out_size;

    const float* x_question = (const float*)d_in[0];
    const float* x_answer   = (const float*)d_in[1];
    const int*   ei_qa      = (const int*)d_in[2];
    const int*   ei_aq      = (const int*)d_in[3];
    const float* w_qa       = (const float*)d_in[4];
    const float* w_aq       = (const float*)d_in[5];
    const int*   eli        = (const int*)d_in[6];
    const float* W_in_q = (const float*)d_in[7],  *b_in_q = (const float*)d_in[8];
    const float* Wk_q = (const float*)d_in[9],  *bk_q = (const float*)d_in[10];
    const float* Wq_q = (const float*)d_in[11], *bq_q = (const float*)d_in[12];
    const float* Wv_q = (const float*)d_in[13], *bv_q = (const float*)d_in[14];
    const float* Wa_q = (const float*)d_in[15], *ba_q = (const float*)d_in[16];
    const float* skip_q = (const float*)d_in[17];
    const float* W_in_a = (const float*)d_in[18], *b_in_a = (const float*)d_in[19];
    const float* Wk_a = (const float*)d_in[20], *bk_a = (const float*)d_in[21];
    const float* Wq_a = (const float*)d_in[22], *bq_a = (const float*)d_in[23];
    const float* Wv_a = (const float*)d_in[24], *bv_a = (const float*)d_in[25];
    const float* Wa_a = (const float*)d_in[26], *ba_a = (const float*)d_in[27];
    const float* skip_a = (const float*)d_in[28];
    const float* a_rel_qa = (const float*)d_in[29];
    const float* m_rel_qa = (const float*)d_in[30];
    const float* p_rel_qa = (const float*)d_in[31];
    const float* a_rel_aq = (const float*)d_in[32];
    const float* m_rel_aq = (const float*)d_in[33];
    const float* p_rel_aq = (const float*)d_in[34];

    float* out = (float*)d_out;

    // ---- workspace layout (f32 elements), ~222.5 MB; guard keeps failures visible ----
    const size_t NEEDED =
        (8ull * NQ * 64 + 4ull * EDGES + 4ull * NQ + 2ull * NBLK + 4ull * (64 * 64 + 64)) * 4ull;
    if (ws_size < NEEDED) return;

    float* ws = (float*)d_ws;
    size_t o = 0;
    auto alloc = [&](size_t nelem) { float* p = ws + o; o += nelem; return p; };
    float* xq   = alloc((size_t)NQ * 64);
    float* xa   = alloc((size_t)NA * 64);
    float* kkq  = alloc((size_t)NQ * 64);   // reused as zq after agg
    float* qqn  = alloc((size_t)NQ * 64);   // reused as aggq (safe alias in agg_kernel)
    float* vvq  = alloc((size_t)NQ * 64);
    float* kka  = alloc((size_t)NA * 64);   // reused as za after agg
    float* qan  = alloc((size_t)NA * 64);   // reused as agga
    float* vva  = alloc((size_t)NA * 64);
    int2*  csr_qa = (int2*)alloc(2ull * EDGES);   // packed {src, bits(w)}
    int2*  csr_aq = (int2*)alloc(2ull * EDGES);
    int* cnt_qa = (int*)alloc(NA);          // cnt_aq must immediately follow (scan uses base+seg*n)
    int* cnt_aq = (int*)alloc(NQ);
    int* off_qa = (int*)alloc(NA);          // off_aq must immediately follow
    int* off_aq = (int*)alloc(NQ);
    int* partials = (int*)alloc(2 * NBLK);
    float* wk_eff_q = alloc(64 * 64); float* bk_eff_q = alloc(64);
    float* wv_eff_q = alloc(64 * 64); float* bv_eff_q = alloc(64);
    float* wk_eff_a = alloc(64 * 64); float* bk_eff_a = alloc(64);
    float* wv_eff_a = alloc(64 * 64); float* bv_eff_a = alloc(64);

    // rank arrays alias xq/xa: CSR build runs BEFORE inproj writes them,
    // stream is serial, so no overlap (1M ints = 4MB << 25.6MB each).
    int* rank_qa = (int*)xq;
    int* rank_aq = (int*)xa;

    float* aggq = qqn;   // aliases (see agg_kernel note)
    float* agga = qan;
    float* zq = kkq;     // kk dead after agg
    float* za = kka;

    const int rowsblk = (NQ + 63) / 64;          // 1563 (NQ == NA)
    const int aggblk  = (NQ * 16 + 255) / 256;   // 6250

    // 1) CSR build FIRST (rank arrays borrow xq/xa space)
    zero_kernel<<<784, 256, 0, stream>>>(cnt_qa, NA, cnt_aq, NQ);
    hist2_kernel<<<dim3(1024, 2), 256, 0, stream>>>(ei_qa, cnt_qa, rank_qa,
                                                    ei_aq, cnt_aq, rank_aq, EDGES);
    scan1_kernel<<<dim3(NBLK, 2), SCAN_BS, 0, stream>>>(cnt_qa, off_qa, partials, NQ);
    scan2_kernel<<<2, 128, 0, stream>>>(partials);
    scan3_kernel<<<dim3(NBLK, 2), SCAN_BS, 0, stream>>>(off_qa, partials, NQ);
    scatter2_kernel<<<dim3(1024, 2), 256, 0, stream>>>(ei_qa, w_qa, rank_qa, off_qa, csr_qa,
                                                       ei_aq, w_aq, rank_aq, off_aq, csr_aq, EDGES);

    // 2) fold a_rel/m_rel (and p_rel/sqrt(D) for K) into projection weights
    fuse_weights_kernel<<<17, 256, 0, stream>>>(Wk_q, bk_q, a_rel_qa, p_rel_qa, wk_eff_q, bk_eff_q);
    fuse_weights_kernel<<<17, 256, 0, stream>>>(Wv_q, bv_q, m_rel_qa, nullptr,  wv_eff_q, bv_eff_q);
    fuse_weights_kernel<<<17, 256, 0, stream>>>(Wk_a, bk_a, a_rel_aq, p_rel_aq, wk_eff_a, bk_eff_a);
    fuse_weights_kernel<<<17, 256, 0, stream>>>(Wv_a, bv_a, m_rel_aq, nullptr,  wv_eff_a, bv_eff_a);

    // 3) input projections + relu (overwrites rank space — safe, stream-serial)
    inproj_kernel<<<rowsblk, 256, 0, stream>>>(x_question, W_in_q, b_in_q, xq, NQ);
    inproj_kernel<<<rowsblk, 256, 0, stream>>>(x_answer,   W_in_a, b_in_a, xa, NA);

    // 4) K/Q/V projections
    proj3_kernel<<<rowsblk, 256, 0, stream>>>(xq, wk_eff_q, bk_eff_q, Wq_q, bq_q,
                                              wv_eff_q, bv_eff_q, kkq, qqn, vvq, NQ);
    proj3_kernel<<<rowsblk, 256, 0, stream>>>(xa, wk_eff_a, bk_eff_a, Wq_a, bq_a,
                                              wv_eff_a, bv_eff_a, kka, qan, vva, NA);

    // 5) fused edge aggregation (gather-based, online softmax, atomic-free)
    agg_kernel<<<aggblk, 256, 0, stream>>>(kkq, vvq, qan, csr_qa, off_qa, cnt_qa, agga, NA);
    agg_kernel<<<aggblk, 256, 0, stream>>>(kka, vva, qqn, csr_aq, off_aq, cnt_aq, aggq, NQ);

    // 6) node update (gelu + linear + gated skip)
    update_kernel<<<rowsblk, 256, 0, stream>>>(aggq, xq, Wa_q, ba_q, skip_q, zq, NQ);
    update_kernel<<<rowsblk, 256, 0, stream>>>(agga, xa, Wa_a, ba_a, skip_a, za, NA);

    // 7) decoder
    decoder_kernel<<<(LSUP * 16 + 255) / 256, 256, 0, stream>>>(zq, za, eli, out, LSUP);
}